// Round 5
// baseline (6874.721 us; speedup 1.0000x reference)
//
#include <hip/hip_runtime.h>

#define NROWS 131072
#define KCB   2048
#define DIM   256
#define NT    24    // virtual-K tiles: 768 / 32

typedef unsigned int u32;
typedef unsigned long long u64;
typedef unsigned short u16;
typedef __attribute__((ext_vector_type(8))) short short8;
typedef __attribute__((ext_vector_type(16))) float f32x16;

__device__ __forceinline__ u32 fkey(float f) {
    u32 b = __float_as_uint(f);
    return (b & 0x80000000u) ? ~b : (b | 0x80000000u);
}
__device__ __forceinline__ u16 bf_rne(float x) {
    u32 u = __float_as_uint(x);
    return (u16)((u + 0x7FFFu + ((u >> 16) & 1u)) >> 16);
}
__device__ __forceinline__ void gload16(const u16* src, u16* dst) {
    __builtin_amdgcn_global_load_lds(
        (const __attribute__((address_space(1))) void*)src,
        (__attribute__((address_space(3))) void*)dst, 16, 0, 0);
}

__device__ __forceinline__ void split4(const float4 v, float inv, ushort4& h, ushort4& l) {
    float e[4] = {v.x * inv, v.y * inv, v.z * inv, v.w * inv};
    u16 hh[4]; u16 ll[4];
    #pragma unroll
    for (int q = 0; q < 4; ++q) {
        hh[q] = bf_rne(e[q]);
        float hf = __uint_as_float(((u32)hh[q]) << 16);
        ll[q] = bf_rne(e[q] - hf);
    }
    h = make_ushort4(hh[0], hh[1], hh[2], hh[3]);
    l = make_ushort4(ll[0], ll[1], ll[2], ll[3]);
}

// ---- K0: normalize z rows -> z_hi/z_lo bf16 ----
__global__ void k_prep_z(const float* __restrict__ z, u16* __restrict__ zhi, u16* __restrict__ zlo) {
    int w = threadIdx.x >> 6, lane = threadIdx.x & 63;
    int row = blockIdx.x * 4 + w;
    float4 v = *(const float4*)(z + (size_t)row * DIM + 4 * lane);
    float ss = v.x * v.x + v.y * v.y + v.z * v.z + v.w * v.w;
    #pragma unroll
    for (int o = 32; o > 0; o >>= 1) ss += __shfl_down(ss, o, 64);
    ss = __shfl(ss, 0, 64);
    float inv = 1.0f / fmaxf(sqrtf(ss), 1e-12f);
    ushort4 h, l;
    split4(v, inv, h, l);
    *(ushort4*)(zhi + (size_t)row * DIM + 4 * lane) = h;
    *(ushort4*)(zlo + (size_t)row * DIM + 4 * lane) = l;
}

// ---- K0b: normalize embedding rows -> e_hi/e_lo bf16 ----
__global__ void k_prep_e(const float* __restrict__ emb, u16* __restrict__ ehi, u16* __restrict__ elo) {
    int w = threadIdx.x >> 6, lane = threadIdx.x & 63;
    int row = blockIdx.x * 4 + w;
    float4 v = *(const float4*)(emb + (size_t)row * DIM + 4 * lane);
    float ss = v.x * v.x + v.y * v.y + v.z * v.z + v.w * v.w;
    #pragma unroll
    for (int o = 32; o > 0; o >>= 1) ss += __shfl_down(ss, o, 64);
    ss = __shfl(ss, 0, 64);
    float inv = 1.0f / fmaxf(sqrtf(ss), 1e-12f);
    ushort4 h, l;
    split4(v, inv, h, l);
    *(ushort4*)(ehi + (size_t)row * DIM + 4 * lane) = h;
    *(ushort4*)(elo + (size_t)row * DIM + 4 * lane) = l;
}

// ---- K2: MFMA GEMM, 256x256 tile, 4 waves (2x2), wave-tile 128x128, BK=32 ----
// LDS: 2 buffers x (A 256x64B + B 256x64B) = 64KB -> 2 blocks/CU (independent
// barrier groups per SIMD -> cross-block LDS/MFMA overlap).
__launch_bounds__(256, 2)
__global__ void k_mfma(const u16* __restrict__ zhi, const u16* __restrict__ zlo,
                       const u16* __restrict__ ehi, const u16* __restrict__ elo,
                       u64* __restrict__ rowmax, u64* __restrict__ colmax) {
    __shared__ __align__(16) u16 lds[2][16384];   // [buf][A:0..8191 | B:8192..16383]
    const int t = threadIdx.x;
    const int lane = t & 63, l31 = lane & 31, lhi = lane >> 5;
    const int w = t >> 6, wr = w >> 1, wc = w & 1;

    // T1: bijective XCD swizzle (nwg=4096): 8 col-tiles of a row-panel -> one XCD
    const int swz = (blockIdx.x & 7) * 512 + (blockIdx.x >> 3);
    const int brow = (swz >> 3) * 256;
    const int bcol = (swz & 7) * 256;

    f32x16 acc[4][4];
    #pragma unroll
    for (int i = 0; i < 4; ++i)
        #pragma unroll
        for (int j = 0; j < 4; ++j)
            #pragma unroll
            for (int r = 0; r < 16; ++r) acc[i][j][r] = 0.f;

    auto stage = [&](int b, int u) {
        const int p = u >> 3;
        const int k0 = (u & 7) * 32;
        const u16* ap = (p == 1) ? zlo : zhi;
        const u16* bp = (p == 2) ? elo : ehi;
        #pragma unroll
        for (int q = 0; q < 4; ++q) {
            int f = q * 256 + t;                 // 16B chunk id, 0..1023
            int r = f >> 2, ps = f & 3, gs = ps ^ (r & 3);
            gload16(ap + (size_t)(brow + r) * DIM + k0 + gs * 8, &lds[b][f * 8]);
        }
        #pragma unroll
        for (int q = 0; q < 4; ++q) {
            int f = q * 256 + t;
            int r = f >> 2, ps = f & 3, gs = ps ^ (r & 3);
            gload16(bp + (size_t)(bcol + r) * DIM + k0 + gs * 8, &lds[b][8192 + f * 8]);
        }
    };

    auto comp = [&](int b) {
        __builtin_amdgcn_s_setprio(1);
        #pragma unroll
        for (int ks = 0; ks < 2; ++ks) {
            short8 af[4], bf4[4];
            #pragma unroll
            for (int i = 0; i < 4; ++i) {
                int r = wr * 128 + i * 32 + l31;
                int seg = (ks * 2 + lhi) ^ (r & 3);
                af[i] = *(const short8*)&lds[b][r * 32 + seg * 8];
            }
            #pragma unroll
            for (int j = 0; j < 4; ++j) {
                int c = wc * 128 + j * 32 + l31;
                int seg = (ks * 2 + lhi) ^ (c & 3);
                bf4[j] = *(const short8*)&lds[b][8192 + c * 32 + seg * 8];
            }
            #pragma unroll
            for (int i = 0; i < 4; ++i)
                #pragma unroll
                for (int j = 0; j < 4; ++j)
                    acc[i][j] = __builtin_amdgcn_mfma_f32_32x32x16_bf16(af[i], bf4[j], acc[i][j], 0, 0, 0);
        }
        __builtin_amdgcn_s_setprio(0);
    };

    // prologue: 2-deep prefetch
    stage(0, 0);
    stage(1, 1);
    asm volatile("s_waitcnt vmcnt(8)" ::: "memory");   // own tile-0 chunks landed
    __builtin_amdgcn_s_barrier();                      // everyone's landed

    for (int u = 0; u < NT; ++u) {
        const int b = u & 1;
        comp(b);
        __builtin_amdgcn_s_barrier();                  // all waves done reading buf b
        if (u + 2 < NT) {
            stage(b, u + 2);
            asm volatile("s_waitcnt vmcnt(8)" ::: "memory");   // tile u+1 landed (own)
        } else if (u + 1 < NT) {
            asm volatile("s_waitcnt vmcnt(0)" ::: "memory");
        }
        __builtin_amdgcn_s_barrier();                  // tile u+1 landed (all waves)
    }

    // ---- epilogue: argmax reductions (LDS now free) ----
    float2* colred = (float2*)&lds[0][0];      // [2 wr][256 cols]  bytes 0..4095
    float2* rowred = (float2*)&lds[0][2048];   // [2 wc][256 rows]  bytes 4096..8191

    // col argmax: per wave over its 128 rows, 4 col-frags
    #pragma unroll
    for (int j = 0; j < 4; ++j) {
        float bv = -3.4e38f; int brw = 0x7FFFFFFF;
        #pragma unroll
        for (int i = 0; i < 4; ++i)
            #pragma unroll
            for (int r = 0; r < 16; ++r) {
                float v = acc[i][j][r];
                int rg = brow + wr * 128 + i * 32 + (r & 3) + 8 * (r >> 2) + 4 * lhi;
                if (v > bv || (v == bv && rg < brw)) { bv = v; brw = rg; }
            }
        float ov = __shfl_xor(bv, 32); int orw = __shfl_xor(brw, 32);
        if (ov > bv || (ov == bv && orw < brw)) { bv = ov; brw = orw; }
        if (lane < 32) colred[wr * 256 + wc * 128 + j * 32 + l31] = make_float2(bv, __int_as_float(brw));
    }

    // row argmax: reduce over 4 col-frags in-lane, then butterfly across 32 lanes
    #pragma unroll
    for (int i = 0; i < 4; ++i) {
        #pragma unroll
        for (int r = 0; r < 16; ++r) {
            float bv = -3.4e38f; int bc = 0x7FFFFFFF;
            #pragma unroll
            for (int j = 0; j < 4; ++j) {
                float v = acc[i][j][r];
                int cg = bcol + wc * 128 + j * 32 + l31;
                if (v > bv || (v == bv && cg < bc)) { bv = v; bc = cg; }
            }
            #pragma unroll
            for (int m = 16; m >= 1; m >>= 1) {
                float ov = __shfl_xor(bv, m);
                int oc = __shfl_xor(bc, m);
                if (ov > bv || (ov == bv && oc < bc)) { bv = ov; bc = oc; }
            }
            if (l31 == 0) {
                int rloc = wr * 128 + i * 32 + (r & 3) + 8 * (r >> 2) + 4 * lhi;
                rowred[wc * 256 + rloc] = make_float2(bv, __int_as_float(bc));
            }
        }
    }
    __syncthreads();

    if (t < 256) {
        float2 e0 = colred[t], e1 = colred[256 + t];
        float bv = e0.x; int brw = __float_as_int(e0.y);
        if (e1.x > bv || (e1.x == bv && __float_as_int(e1.y) < brw)) { bv = e1.x; brw = __float_as_int(e1.y); }
        atomicMax(colmax + bcol + t, ((u64)fkey(bv) << 32) | (u64)(~(u32)brw));

        float2 r0 = rowred[t], r1 = rowred[256 + t];
        float rv = r0.x; int rc = __float_as_int(r0.y);
        if (r1.x > rv || (r1.x == rv && __float_as_int(r1.y) < rc)) { rv = r1.x; rc = __float_as_int(r1.y); }
        atomicMax(rowmax + brow + t, ((u64)fkey(rv) << 32) | (u64)(~(u32)rc));
    }
}

// ---- K3: gather z_q, write out0, loss partials, histogram ----
__global__ void k_gather(const float* __restrict__ z, const float* __restrict__ emb,
                         const u64* __restrict__ rowmax, float* __restrict__ zq_out,
                         int* __restrict__ counts, float* __restrict__ partials) {
    __shared__ float red[256];
    int t = threadIdx.x;
    int lane = t & 63, w = t >> 6;
    int base = blockIdx.x * 64;
    float acc = 0.f;
    for (int r = 0; r < 16; ++r) {
        int row = base + w * 16 + r;
        int ix = (int)(~(u32)(rowmax[row] & 0xFFFFFFFFull));
        float4 e  = *(const float4*)(emb + (size_t)ix * DIM + 4 * lane);
        float4 zv = *(const float4*)(z + (size_t)row * DIM + 4 * lane);
        float4 o;
        o.x = zv.x + (e.x - zv.x); o.y = zv.y + (e.y - zv.y);
        o.z = zv.z + (e.z - zv.z); o.w = zv.w + (e.w - zv.w);
        *(float4*)(zq_out + (size_t)row * DIM + 4 * lane) = o;
        float dx = e.x - zv.x, dy = e.y - zv.y, dz = e.z - zv.z, dw = e.w - zv.w;
        acc += dx * dx + dy * dy + dz * dz + dw * dw;
        if (lane == 0) atomicAdd(counts + ix, 1);
    }
    red[t] = acc;
    __syncthreads();
    #pragma unroll
    for (int o = 128; o > 0; o >>= 1) { if (t < o) red[t] += red[t + o]; __syncthreads(); }
    if (t == 0) partials[blockIdx.x] = red[0];
}

// ---- K4: final loss reduce ----
__global__ void k_loss(const float* __restrict__ partials, float* __restrict__ out_loss) {
    __shared__ float red[256];
    int t = threadIdx.x;
    float a = 0.f;
    for (int i = t; i < 2048; i += 256) a += partials[i];
    red[t] = a;
    __syncthreads();
    #pragma unroll
    for (int o = 128; o > 0; o >>= 1) { if (t < o) red[t] += red[t + o]; __syncthreads(); }
    if (t == 0) out_loss[0] = 1.25f * (red[0] / 33554432.0f);
}

// ---- K5: finalize new_embedding + new_embed_prob ----
__global__ void k_final(const float* __restrict__ z, const float* __restrict__ emb,
                        const float* __restrict__ eprob, const int* __restrict__ counts,
                        const u64* __restrict__ colmax,
                        float* __restrict__ out_emb, float* __restrict__ out_prob) {
    int k = blockIdx.x, lane = threadIdx.x;   // 2048 x 64
    int r = (int)(~(u32)(colmax[k] & 0xFFFFFFFFull));
    float avg = (float)counts[k] * (1.0f / (float)NROWS);
    float nep = eprob[k] * 0.99f + avg * 0.01f;
    float reinit = expf(-(((nep * 2048.0f) * 10.0f) / 0.01f) - 0.001f);
    float4 ev = *(const float4*)(emb + (size_t)k * DIM + 4 * lane);
    float4 zv = *(const float4*)(z + (size_t)r * DIM + 4 * lane);
    float4 o;
    o.x = ev.x * (1.f - reinit) + zv.x * reinit;
    o.y = ev.y * (1.f - reinit) + zv.y * reinit;
    o.z = ev.z * (1.f - reinit) + zv.z * reinit;
    o.w = ev.w * (1.f - reinit) + zv.w * reinit;
    *(float4*)(out_emb + (size_t)k * DIM + 4 * lane) = o;
    if (lane == 0) out_prob[k] = nep;
}

extern "C" void kernel_launch(void* const* d_in, const int* in_sizes, int n_in,
                              void* d_out, int out_size, void* d_ws, size_t ws_size,
                              hipStream_t stream) {
    const float* z   = (const float*)d_in[0];
    const float* emb = (const float*)d_in[1];
    const float* epr = (const float*)d_in[2];

    float* out      = (float*)d_out;
    float* out_zq   = out;                                // NROWS*DIM floats
    float* out_loss = out + (size_t)NROWS * DIM;          // 1
    float* out_emb  = out_loss + 1;                       // KCB*DIM
    float* out_prob = out_emb + (size_t)KCB * DIM;        // KCB

    // z_hi/z_lo live in the zq region of d_out (exactly 134,217,728 bytes);
    // k_gather overwrites it after k_mfma has consumed it.
    u16* zhi = (u16*)d_out;
    u16* zlo = zhi + (size_t)NROWS * DIM;

    char* ws = (char*)d_ws;
    u16*   ehi    = (u16*)  (ws + 0);          // 1 MB
    u16*   elo    = (u16*)  (ws + 1048576);    // 1 MB
    u64*   rowmax = (u64*)  (ws + 2097152);    // 1 MB
    u64*   colmax = (u64*)  (ws + 3145728);    // 16 KB
    int*   counts = (int*)  (ws + 3162112);    // 8 KB
    float* parts  = (float*)(ws + 3170304);    // 8 KB

    hipMemsetAsync(rowmax, 0, 1048576 + 16384 + 8192, stream);

    k_prep_z<<<NROWS / 4, 256, 0, stream>>>(z, zhi, zlo);
    k_prep_e<<<KCB / 4, 256, 0, stream>>>(emb, ehi, elo);
    k_mfma<<<(NROWS / 256) * 8, 256, 0, stream>>>(zhi, zlo, ehi, elo, rowmax, colmax);
    k_gather<<<NROWS / 64, 256, 0, stream>>>(z, emb, rowmax, out_zq, counts, parts);
    k_loss<<<1, 256, 0, stream>>>(parts, out_loss);
    k_final<<<KCB, 64, 0, stream>>>(z, emb, epr, counts, colmax, out_emb, out_prob);
}

// Round 6
// 1003.035 us; speedup vs baseline: 6.8539x; 6.8539x over previous
//
#include <hip/hip_runtime.h>

#define NROWS 131072
#define KCB   2048
#define DIM   256
#define NT    24    // virtual-K tiles: 768 / 32

typedef unsigned int u32;
typedef unsigned long long u64;
typedef unsigned short u16;
typedef __attribute__((ext_vector_type(8))) short short8;
typedef __attribute__((ext_vector_type(16))) float f32x16;

__device__ __forceinline__ u32 fkey(float f) {
    u32 b = __float_as_uint(f);
    return (b & 0x80000000u) ? ~b : (b | 0x80000000u);
}
__device__ __forceinline__ u16 bf_rne(float x) {
    u32 u = __float_as_uint(x);
    return (u16)((u + 0x7FFFu + ((u >> 16) & 1u)) >> 16);
}
__device__ __forceinline__ void gload16(const u16* src, u16* dst) {
    __builtin_amdgcn_global_load_lds(
        (const __attribute__((address_space(1))) void*)src,
        (__attribute__((address_space(3))) void*)dst, 16, 0, 0);
}

__device__ __forceinline__ void split4(const float4 v, float inv, ushort4& h, ushort4& l) {
    float e[4] = {v.x * inv, v.y * inv, v.z * inv, v.w * inv};
    u16 hh[4]; u16 ll[4];
    #pragma unroll
    for (int q = 0; q < 4; ++q) {
        hh[q] = bf_rne(e[q]);
        float hf = __uint_as_float(((u32)hh[q]) << 16);
        ll[q] = bf_rne(e[q] - hf);
    }
    h = make_ushort4(hh[0], hh[1], hh[2], hh[3]);
    l = make_ushort4(ll[0], ll[1], ll[2], ll[3]);
}

// ---- K0: normalize z rows -> z_hi/z_lo bf16 ----
__global__ void k_prep_z(const float* __restrict__ z, u16* __restrict__ zhi, u16* __restrict__ zlo) {
    int w = threadIdx.x >> 6, lane = threadIdx.x & 63;
    int row = blockIdx.x * 4 + w;
    float4 v = *(const float4*)(z + (size_t)row * DIM + 4 * lane);
    float ss = v.x * v.x + v.y * v.y + v.z * v.z + v.w * v.w;
    #pragma unroll
    for (int o = 32; o > 0; o >>= 1) ss += __shfl_down(ss, o, 64);
    ss = __shfl(ss, 0, 64);
    float inv = 1.0f / fmaxf(sqrtf(ss), 1e-12f);
    ushort4 h, l;
    split4(v, inv, h, l);
    *(ushort4*)(zhi + (size_t)row * DIM + 4 * lane) = h;
    *(ushort4*)(zlo + (size_t)row * DIM + 4 * lane) = l;
}

// ---- K0b: normalize embedding rows -> e_hi/e_lo bf16 ----
__global__ void k_prep_e(const float* __restrict__ emb, u16* __restrict__ ehi, u16* __restrict__ elo) {
    int w = threadIdx.x >> 6, lane = threadIdx.x & 63;
    int row = blockIdx.x * 4 + w;
    float4 v = *(const float4*)(emb + (size_t)row * DIM + 4 * lane);
    float ss = v.x * v.x + v.y * v.y + v.z * v.z + v.w * v.w;
    #pragma unroll
    for (int o = 32; o > 0; o >>= 1) ss += __shfl_down(ss, o, 64);
    ss = __shfl(ss, 0, 64);
    float inv = 1.0f / fmaxf(sqrtf(ss), 1e-12f);
    ushort4 h, l;
    split4(v, inv, h, l);
    *(ushort4*)(ehi + (size_t)row * DIM + 4 * lane) = h;
    *(ushort4*)(elo + (size_t)row * DIM + 4 * lane) = l;
}

// ---- K2: MFMA GEMM, 256x128 tile, 4 waves (2 row x 2 col), wave-tile 128x64 ----
// LDS: 2 buf x (A 256x64B=16KB + B 128x64B=8KB) = 48KB -> 2 blocks/CU. The two
// waves sharing a SIMD come from DIFFERENT blocks (independent barrier groups)
// so one block's MFMA burst overlaps the other's stage/barrier window.
// Store-side seg swizzle s(r)=(r>>1)&3: each 16-lane b128 read group covers all
// eight 4-bank windows exactly twice (minimal aliasing).
__launch_bounds__(256, 2)
__global__ void k_mfma(const u16* __restrict__ zhi, const u16* __restrict__ zlo,
                       const u16* __restrict__ ehi, const u16* __restrict__ elo,
                       u64* __restrict__ rowmax, u64* __restrict__ colmax) {
    __shared__ __align__(16) u16 lds[2][12288];   // [buf][A:0..8191 | B:8192..12287]
    const int t = threadIdx.x;
    const int lane = t & 63, l31 = lane & 31, lhi = lane >> 5;
    const int w = t >> 6, wr = w >> 1, wc = w & 1;

    // T1: bijective XCD swizzle (nwg=8192, 1024/XCD): 16 col-tiles of one
    // row-panel run consecutively on one XCD -> A-panel + full B table L2-hot.
    const int swz = (blockIdx.x & 7) * 1024 + (blockIdx.x >> 3);
    const int brow = (swz >> 4) * 256;
    const int bcol = (swz & 15) * 128;

    f32x16 acc[4][2];
    #pragma unroll
    for (int i = 0; i < 4; ++i)
        #pragma unroll
        for (int j = 0; j < 2; ++j)
            #pragma unroll
            for (int r = 0; r < 16; ++r) acc[i][j][r] = 0.f;

    auto stage = [&](int b, int u) {
        const int p = u >> 3;
        const int k0 = (u & 7) * 32;
        const u16* ap = (p == 1) ? zlo : zhi;
        const u16* bp = (p == 2) ? elo : ehi;
        #pragma unroll
        for (int q = 0; q < 4; ++q) {            // A: 1024 16B chunks
            int f = q * 256 + t;
            int r = f >> 2, ps = f & 3, gs = ps ^ ((r >> 1) & 3);
            gload16(ap + (size_t)(brow + r) * DIM + k0 + gs * 8, &lds[b][f * 8]);
        }
        #pragma unroll
        for (int q = 0; q < 2; ++q) {            // B: 512 16B chunks
            int f = q * 256 + t;
            int r = f >> 2, ps = f & 3, gs = ps ^ ((r >> 1) & 3);
            gload16(bp + (size_t)(bcol + r) * DIM + k0 + gs * 8, &lds[b][8192 + f * 8]);
        }
    };

    auto comp = [&](int b) {
        __builtin_amdgcn_s_setprio(1);
        #pragma unroll
        for (int ks = 0; ks < 2; ++ks) {
            short8 af[4], bf2[2];
            #pragma unroll
            for (int i = 0; i < 4; ++i) {
                int r = wr * 128 + i * 32 + l31;
                int seg = (ks * 2 + lhi) ^ ((r >> 1) & 3);
                af[i] = *(const short8*)&lds[b][r * 32 + seg * 8];
            }
            #pragma unroll
            for (int j = 0; j < 2; ++j) {
                int c = wc * 64 + j * 32 + l31;
                int seg = (ks * 2 + lhi) ^ ((c >> 1) & 3);
                bf2[j] = *(const short8*)&lds[b][8192 + c * 32 + seg * 8];
            }
            #pragma unroll
            for (int i = 0; i < 4; ++i)
                #pragma unroll
                for (int j = 0; j < 2; ++j)
                    acc[i][j] = __builtin_amdgcn_mfma_f32_32x32x16_bf16(af[i], bf2[j], acc[i][j], 0, 0, 0);
        }
        __builtin_amdgcn_s_setprio(0);
    };

    // prologue: 2-deep prefetch (6 loads per stage per thread)
    stage(0, 0);
    stage(1, 1);
    asm volatile("s_waitcnt vmcnt(6)" ::: "memory");   // tile 0 landed (own lanes)
    __builtin_amdgcn_s_barrier();                      // landed for all waves

    for (int u = 0; u < NT; ++u) {
        const int b = u & 1;
        comp(b);
        __builtin_amdgcn_s_barrier();                  // all waves done reading buf b
        if (u + 2 < NT) {
            stage(b, u + 2);
            asm volatile("s_waitcnt vmcnt(6)" ::: "memory");   // tile u+1 landed
        } else if (u + 1 < NT) {
            asm volatile("s_waitcnt vmcnt(0)" ::: "memory");
        }
        __builtin_amdgcn_s_barrier();                  // tile u+1 visible to all
    }

    // ---- epilogue: argmax reductions (LDS now free) ----
    float2* colred = (float2*)&lds[0][0];      // [2 wr][128 cols]  bytes 0..2047
    float2* rowred = (float2*)&lds[0][1024];   // [2 wc][256 rows]  bytes 2048..6143

    // col argmax: per wave over its 128 rows, 2 col-frags
    #pragma unroll
    for (int j = 0; j < 2; ++j) {
        float bv = -3.4e38f; int brw = 0x7FFFFFFF;
        #pragma unroll
        for (int i = 0; i < 4; ++i)
            #pragma unroll
            for (int r = 0; r < 16; ++r) {
                float v = acc[i][j][r];
                int rg = brow + wr * 128 + i * 32 + (r & 3) + 8 * (r >> 2) + 4 * lhi;
                if (v > bv || (v == bv && rg < brw)) { bv = v; brw = rg; }
            }
        float ov = __shfl_xor(bv, 32); int orw = __shfl_xor(brw, 32);
        if (ov > bv || (ov == bv && orw < brw)) { bv = ov; brw = orw; }
        if (lane < 32) colred[wr * 128 + wc * 64 + j * 32 + l31] = make_float2(bv, __int_as_float(brw));
    }

    // row argmax: reduce over 2 col-frags in-lane, then butterfly across 32 lanes
    #pragma unroll
    for (int i = 0; i < 4; ++i) {
        #pragma unroll
        for (int r = 0; r < 16; ++r) {
            float bv = -3.4e38f; int bc = 0x7FFFFFFF;
            #pragma unroll
            for (int j = 0; j < 2; ++j) {
                float v = acc[i][j][r];
                int cg = bcol + wc * 64 + j * 32 + l31;
                if (v > bv || (v == bv && cg < bc)) { bv = v; bc = cg; }
            }
            #pragma unroll
            for (int m = 16; m >= 1; m >>= 1) {
                float ov = __shfl_xor(bv, m);
                int oc = __shfl_xor(bc, m);
                if (ov > bv || (ov == bv && oc < bc)) { bv = ov; bc = oc; }
            }
            if (l31 == 0) {
                int rloc = wr * 128 + i * 32 + (r & 3) + 8 * (r >> 2) + 4 * lhi;
                rowred[wc * 256 + rloc] = make_float2(bv, __int_as_float(bc));
            }
        }
    }
    __syncthreads();

    if (t < 128) {
        float2 e0 = colred[t], e1 = colred[128 + t];
        float bv = e0.x; int brw = __float_as_int(e0.y);
        if (e1.x > bv || (e1.x == bv && __float_as_int(e1.y) < brw)) { bv = e1.x; brw = __float_as_int(e1.y); }
        atomicMax(colmax + bcol + t, ((u64)fkey(bv) << 32) | (u64)(~(u32)brw));
    }
    if (t < 256) {
        float2 r0 = rowred[t], r1 = rowred[256 + t];
        float rv = r0.x; int rc = __float_as_int(r0.y);
        if (r1.x > rv || (r1.x == rv && __float_as_int(r1.y) < rc)) { rv = r1.x; rc = __float_as_int(r1.y); }
        atomicMax(rowmax + brow + t, ((u64)fkey(rv) << 32) | (u64)(~(u32)rc));
    }
}

// ---- K3: gather z_q, write out0, loss partials, histogram ----
__global__ void k_gather(const float* __restrict__ z, const float* __restrict__ emb,
                         const u64* __restrict__ rowmax, float* __restrict__ zq_out,
                         int* __restrict__ counts, float* __restrict__ partials) {
    __shared__ float red[256];
    int t = threadIdx.x;
    int lane = t & 63, w = t >> 6;
    int base = blockIdx.x * 64;
    float acc = 0.f;
    for (int r = 0; r < 16; ++r) {
        int row = base + w * 16 + r;
        int ix = (int)(~(u32)(rowmax[row] & 0xFFFFFFFFull));
        float4 e  = *(const float4*)(emb + (size_t)ix * DIM + 4 * lane);
        float4 zv = *(const float4*)(z + (size_t)row * DIM + 4 * lane);
        float4 o;
        o.x = zv.x + (e.x - zv.x); o.y = zv.y + (e.y - zv.y);
        o.z = zv.z + (e.z - zv.z); o.w = zv.w + (e.w - zv.w);
        *(float4*)(zq_out + (size_t)row * DIM + 4 * lane) = o;
        float dx = e.x - zv.x, dy = e.y - zv.y, dz = e.z - zv.z, dw = e.w - zv.w;
        acc += dx * dx + dy * dy + dz * dz + dw * dw;
        if (lane == 0) atomicAdd(counts + ix, 1);
    }
    red[t] = acc;
    __syncthreads();
    #pragma unroll
    for (int o = 128; o > 0; o >>= 1) { if (t < o) red[t] += red[t + o]; __syncthreads(); }
    if (t == 0) partials[blockIdx.x] = red[0];
}

// ---- K4: final loss reduce ----
__global__ void k_loss(const float* __restrict__ partials, float* __restrict__ out_loss) {
    __shared__ float red[256];
    int t = threadIdx.x;
    float a = 0.f;
    for (int i = t; i < 2048; i += 256) a += partials[i];
    red[t] = a;
    __syncthreads();
    #pragma unroll
    for (int o = 128; o > 0; o >>= 1) { if (t < o) red[t] += red[t + o]; __syncthreads(); }
    if (t == 0) out_loss[0] = 1.25f * (red[0] / 33554432.0f);
}

// ---- K5: finalize new_embedding + new_embed_prob ----
__global__ void k_final(const float* __restrict__ z, const float* __restrict__ emb,
                        const float* __restrict__ eprob, const int* __restrict__ counts,
                        const u64* __restrict__ colmax,
                        float* __restrict__ out_emb, float* __restrict__ out_prob) {
    int k = blockIdx.x, lane = threadIdx.x;   // 2048 x 64
    int r = (int)(~(u32)(colmax[k] & 0xFFFFFFFFull));
    float avg = (float)counts[k] * (1.0f / (float)NROWS);
    float nep = eprob[k] * 0.99f + avg * 0.01f;
    float reinit = expf(-(((nep * 2048.0f) * 10.0f) / 0.01f) - 0.001f);
    float4 ev = *(const float4*)(emb + (size_t)k * DIM + 4 * lane);
    float4 zv = *(const float4*)(z + (size_t)r * DIM + 4 * lane);
    float4 o;
    o.x = ev.x * (1.f - reinit) + zv.x * reinit;
    o.y = ev.y * (1.f - reinit) + zv.y * reinit;
    o.z = ev.z * (1.f - reinit) + zv.z * reinit;
    o.w = ev.w * (1.f - reinit) + zv.w * reinit;
    *(float4*)(out_emb + (size_t)k * DIM + 4 * lane) = o;
    if (lane == 0) out_prob[k] = nep;
}

extern "C" void kernel_launch(void* const* d_in, const int* in_sizes, int n_in,
                              void* d_out, int out_size, void* d_ws, size_t ws_size,
                              hipStream_t stream) {
    const float* z   = (const float*)d_in[0];
    const float* emb = (const float*)d_in[1];
    const float* epr = (const float*)d_in[2];

    float* out      = (float*)d_out;
    float* out_zq   = out;                                // NROWS*DIM floats
    float* out_loss = out + (size_t)NROWS * DIM;          // 1
    float* out_emb  = out_loss + 1;                       // KCB*DIM
    float* out_prob = out_emb + (size_t)KCB * DIM;        // KCB

    // z_hi/z_lo live in the zq region of d_out (exactly 134,217,728 bytes);
    // k_gather overwrites it after k_mfma has consumed it.
    u16* zhi = (u16*)d_out;
    u16* zlo = zhi + (size_t)NROWS * DIM;

    char* ws = (char*)d_ws;
    u16*   ehi    = (u16*)  (ws + 0);          // 1 MB
    u16*   elo    = (u16*)  (ws + 1048576);    // 1 MB
    u64*   rowmax = (u64*)  (ws + 2097152);    // 1 MB
    u64*   colmax = (u64*)  (ws + 3145728);    // 16 KB
    int*   counts = (int*)  (ws + 3162112);    // 8 KB
    float* parts  = (float*)(ws + 3170304);    // 8 KB

    hipMemsetAsync(rowmax, 0, 1048576 + 16384 + 8192, stream);

    k_prep_z<<<NROWS / 4, 256, 0, stream>>>(z, zhi, zlo);
    k_prep_e<<<KCB / 4, 256, 0, stream>>>(emb, ehi, elo);
    k_mfma<<<(NROWS / 256) * (KCB / 128), 256, 0, stream>>>(zhi, zlo, ehi, elo, rowmax, colmax);
    k_gather<<<NROWS / 64, 256, 0, stream>>>(z, emb, rowmax, out_zq, counts, parts);
    k_loss<<<1, 256, 0, stream>>>(parts, out_loss);
    k_final<<<KCB, 64, 0, stream>>>(z, emb, epr, counts, colmax, out_emb, out_prob);
}